// Round 14
// baseline (116.354 us; speedup 1.0000x reference)
//
#include <hip/hip_runtime.h>
#include <hip/hip_bf16.h>
#include <math.h>

#define BS 256
#define J  50
#define O  50
#define MM 50
#define E  64
#define NSEQ (BS*J)     // 12800
#define G4 (4*E)        // 256
#define DD 192          // 3*E
#define NBATCH (NSEQ/32) // 400 batches of 32 sequences
#define NPAIR (NBATCH/2) // 200 workgroups, 2 batches each
#define KH 88            // padded K row stride (176B) — r7/r10-validated layout
#define LOG2E 1.442695041f

typedef _Float16 f16x8 __attribute__((ext_vector_type(8)));
typedef _Float16 f16x4 __attribute__((ext_vector_type(4)));
typedef _Float16 half2v __attribute__((ext_vector_type(2)));
typedef float f32x16 __attribute__((ext_vector_type(16)));

// persistent device scratch (fully rewritten every call)
__device__ float g_u[G4], g_v[G4], g_w[G4];
__device__ float g_h0[E], g_c0[E];
__device__ __align__(16) float g_hc[DD];
__device__ float g_wproj[8];
__device__ float g_cproj;
__device__ float g_je[NSEQ * E];
__device__ int   g_idx[NSEQ];

__device__ __forceinline__ float RCP(float x) {
#if __has_builtin(__builtin_amdgcn_rcpf)
    return __builtin_amdgcn_rcpf(x);
#else
    return __fdividef(1.f, x);
#endif
}
__device__ __forceinline__ float EXP2(float x) {
#if __has_builtin(__builtin_amdgcn_exp2f)
    return __builtin_amdgcn_exp2f(x);
#else
    return exp2f(x);
#endif
}
__device__ __forceinline__ float sigm(float x) {
    return RCP(1.f + __expf(-x));
}
__device__ __forceinline__ float ftanh(float x) {
    float e = __expf(-2.f * x);
    return fmaf(2.f, RCP(1.f + e), -1.f);
}

__device__ __forceinline__ half2v PK(float a, float b) {
#if __has_builtin(__builtin_amdgcn_cvt_pkrtz)
    auto t = __builtin_amdgcn_cvt_pkrtz(a, b);   // __fp16 ext_vector_type(2)
    return __builtin_bit_cast(half2v, t);
#else
    half2v r; r[0] = (_Float16)a; r[1] = (_Float16)b; return r;
#endif
}

// ---------------------------------------------------------------------------
// Kernel A: collapsed input projection (u,v,w), shared first LSTM step
// (h0,c0), Set2Set constant hidden, attention-logit projection, in-block
// LDS-atomic counting sort. 1024 threads: sort passes take 13 iterations
// instead of 50 (r12's single biggest precompute cost).
// ---------------------------------------------------------------------------
__global__ __launch_bounds__(1024) void precompute_kernel(
    const float* __restrict__ Wmac, const float* __restrict__ bmac,
    const float* __restrict__ Wjt,  const float* __restrict__ bjt,
    const float* __restrict__ Wih,  const float* __restrict__ bih,
    const float* __restrict__ bhh,
    const float* __restrict__ Wdyn, const float* __restrict__ bdyn,
    const float* __restrict__ bih2, const float* __restrict__ bhh2,
    const int*   __restrict__ job_state)
{
    __shared__ float s_hc[DD];
    __shared__ int cnt51[51], cur51[51];
    const int g = threadIdx.x;  // 0..1023

    if (g < 51) cnt51[g] = 0;

    if (g < G4) {
        const float* row = &Wih[g * (2 * E)];
        float u = 0.f, v = 0.f, w = 0.f;
        #pragma unroll 8
        for (int e = 0; e < E; ++e) {
            float w0 = row[e], w1 = row[E + e];
            u = fmaf(w0, Wmac[e], u);
            v = fmaf(w1, Wjt[e], v);
            w = fmaf(w0, bmac[e], fmaf(w1, bjt[e], w));
        }
        g_u[g] = u;
        g_v[g] = v;
        g_w[g] = w + bih[g] + bhh[g];
    }

    // Set2Set with q_star=h=c=0: gates = bih2+bhh2 (constant)
    if (g < DD) {
        float gi = bih2[g]          + bhh2[g];
        float gg = bih2[2 * DD + g] + bhh2[2 * DD + g];
        float go = bih2[3 * DD + g] + bhh2[3 * DD + g];
        float c  = sigm(gi) * ftanh(gg);
        float h  = sigm(go) * ftanh(c);
        s_hc[g] = h;
        g_hc[g] = h;
    }
    __syncthreads();

    // shared t=0 LSTM step: inputs are constants (pv = M, jv = 0), h=c=0
    if (g < E) {
        float ai = fmaf((float)MM, g_u[g],         g_w[g]);
        float ag = fmaf((float)MM, g_u[2 * E + g], g_w[2 * E + g]);
        float ao = fmaf((float)MM, g_u[3 * E + g], g_w[3 * E + g]);
        float c0 = sigm(ai) * ftanh(ag);
        float h0 = sigm(ao) * ftanh(c0);
        g_h0[g] = h0;
        g_c0[g] = c0;
    }

    if (g < 8) {
        float s = 0.f;
        if (g < 7) {
            for (int d = 0; d < 2 * E; ++d) s = fmaf(s_hc[E + d], Wdyn[d * 7 + g], s);
        }
        g_wproj[g] = s;
    }
    if (g == 8) {
        float s = 0.f;
        for (int d = 0; d < 2 * E; ++d) s = fmaf(s_hc[E + d], bdyn[d], s);
        g_cproj = s;
    }

    // ---- counting sort by job_state (ascending js = descending length) ----
    for (int s = g; s < NSEQ; s += 1024)
        atomicAdd(&cnt51[job_state[s]], 1);
    __syncthreads();
    if (g == 0) {
        int run = 0;
        for (int b2 = 0; b2 < 51; ++b2) { cur51[b2] = run; run += cnt51[b2]; }
    }
    __syncthreads();
    for (int s = g; s < NSEQ; s += 1024) {
        int pos = atomicAdd(&cur51[job_state[s]], 1);
        g_idx[pos] = s;
    }
}

// ---------------------------------------------------------------------------
// Kernel B: MFMA-batched LSTM with INTRA-WG BATCH PAIRING. 200 WGs (1/CU);
// each processes batches 2b and 2b+1 (adjacent lengths after the sort) in one
// loop body: the two recurrences are independent dataflow, so A's MFMA/
// activation chain hides under B's and vice versa (the r12 wall was 50 steps
// x a ~2000cy under-overlapped chain). A-fragments (weights) are SHARED; only
// state/accumulators duplicate. __launch_bounds__(256,1) -> 512-reg budget,
// no r9-style spill. One shared barrier per step covers both batches.
// Per step per batch: double-buffered H, exp2-domain gates (A pre-scaled by
// log2e, 2*log2e for g-rows), shared-denominator activations (8 trans/unit).
// ---------------------------------------------------------------------------
__global__ __launch_bounds__(256, 1) void lstm_kernel(
    const float* __restrict__ job_times,   // [BS*J, O]
    const int*   __restrict__ precedence,  // [BS*J, M]
    const int*   __restrict__ job_state,   // [BS*J]
    const float* __restrict__ Whh)         // [256, 64]
{
    __shared__ alignas(16) _Float16 HA[2][32 * KH];
    __shared__ alignas(16) _Float16 HB[2][32 * KH];
    __shared__ half2v HinA[32][O + 1];
    __shared__ half2v HinB[32][O + 1];
    __shared__ int sidA[32], tmxA[32], sidB[32], tmxB[32];
    __shared__ int tmax_sh;

    const int tid  = threadIdx.x;
    const int lane = tid & 63;
    const int wid  = tid >> 6;          // 0..3
    const int n    = lane & 31;         // sequence column (D/B col = lane&31)
    const int hi   = lane >> 5;

    // ---- loop-invariant A fragments (row-permuted G_ext, f16), 2 tiles,
    //      SHARED between the two batches ----
    const int rl = lane & 31;
    const float sc = ((rl >> 3) == 2) ? (2.f * LOG2E) : LOG2E;  // g-gate rows 2x
    f16x8 a[2][5];
    #pragma unroll
    for (int ti = 0; ti < 2; ++ti) {
        const int tile = wid + 4 * ti;                       // 0..7
        const int grow = (rl >> 3) * 64 + 8 * tile + (rl & 7);
        const float* wr = Whh + grow * 64 + hi * 8;
        #pragma unroll
        for (int kt = 0; kt < 4; ++kt) {
            f16x8 t;
            #pragma unroll
            for (int j = 0; j < 8; ++j) t[j] = (_Float16)(sc * wr[kt * 16 + j]);
            a[ti][kt] = t;
        }
        f16x8 t;
        #pragma unroll
        for (int j = 0; j < 8; ++j) t[j] = (_Float16)0.f;
        if (hi == 0) {              // k=64,65,66 -> u,v,w columns (scaled)
            t[0] = (_Float16)(sc * g_u[grow]);
            t[1] = (_Float16)(sc * g_v[grow]);
            t[2] = (_Float16)(sc * g_w[grow]);
        }
        a[ti][4] = t;
    }

    // this lane's units: tile0 -> ub0..ub0+3, tile1 -> ub1..ub1+3
    const int ub0 = 8 * wid + 4 * hi;
    const int ub1 = ub0 + 32;
    float h0r[2][4], c0r[2][4];
    #pragma unroll
    for (int x = 0; x < 4; ++x) {
        c0r[0][x] = g_c0[ub0 + x]; h0r[0][x] = g_h0[ub0 + x];
        c0r[1][x] = g_c0[ub1 + x]; h0r[1][x] = g_h0[ub1 + x];
    }
    f16x4 h0v0, h0v1;
    #pragma unroll
    for (int x = 0; x < 4; ++x) { h0v0[x] = (_Float16)h0r[0][x]; h0v1[x] = (_Float16)h0r[1][x]; }

    const int b = blockIdx.x;           // pair id: batches 2b, 2b+1

    // ---- batch-pair init ----
    if (tid < 32) {
        int s = g_idx[(2 * b) * 32 + tid];
        sidA[tid] = s;
        tmxA[tid] = O - job_state[s];
    } else if (tid < 64) {
        int m = tid - 32;
        int s = g_idx[(2 * b + 1) * 32 + m];
        sidB[m] = s;
        tmxB[m] = O - job_state[s];
    }
    {   // zero all four H buffers (covers pad rows 67..87)
        for (int i = tid; i < 2 * 32 * KH / 2; i += 256) {
            ((int*)HA)[i] = 0;
            ((int*)HB)[i] = 0;
        }
    }
    __syncthreads();
    if (tid == 0) {
        int m = 0;
        for (int i = 0; i < 32; ++i) m = max(m, max(tmxA[i], tmxB[i]));
        tmax_sh = m;
    }
    // stage per-step inputs for both batches
    for (int i = tid; i < 2 * 32 * O; i += 256) {
        const int bb = i / (32 * O);   // 0 = A, 1 = B
        const int r  = i % (32 * O);
        const int n2 = r / O;
        const int t2 = r % O + 1;      // 1..50
        const int sid2 = bb ? sidB[n2] : sidA[n2];
        const int o = O - t2;
        half2v pk = PK((float)precedence[sid2 * MM + o],
                       job_times[sid2 * O + o]);
        if (bb) {
            HinB[n2][t2] = pk;
            if (t2 == 1) *reinterpret_cast<half2v*>(&HB[0][n2 * KH + 64]) = pk;
        } else {
            HinA[n2][t2] = pk;
            if (t2 == 1) *reinterpret_cast<half2v*>(&HA[0][n2 * KH + 64]) = pk;
        }
    }
    {   // write h0 into HA[0] and HB[0]
        *reinterpret_cast<f16x4*>(&HA[0][n * KH + ub0]) = h0v0;
        *reinterpret_cast<f16x4*>(&HA[0][n * KH + ub1]) = h0v1;
        *reinterpret_cast<f16x4*>(&HB[0][n * KH + ub0]) = h0v0;
        *reinterpret_cast<f16x4*>(&HB[0][n * KH + ub1]) = h0v1;
    }
    if (tid < 32) {
        HA[0][tid * KH + 66] = (_Float16)1.f;
        HA[1][tid * KH + 66] = (_Float16)1.f;
    } else if (tid < 64) {
        int m = tid - 32;
        HB[0][m * KH + 66] = (_Float16)1.f;
        HB[1][m * KH + 66] = (_Float16)1.f;
    }
    __syncthreads();

    const int tmaxM  = tmax_sh;
    const int tmaxnA = tmxA[n], tmaxnB = tmxB[n];
    const int sidnA  = sidA[n], sidnB  = sidB[n];

    float crA[2][4], hrA[2][4], crB[2][4], hrB[2][4];
    #pragma unroll
    for (int x = 0; x < 4; ++x) {
        crA[0][x] = c0r[0][x]; hrA[0][x] = h0r[0][x];
        crA[1][x] = c0r[1][x]; hrA[1][x] = h0r[1][x];
        crB[0][x] = c0r[0][x]; hrB[0][x] = h0r[0][x];
        crB[1][x] = c0r[1][x]; hrB[1][x] = h0r[1][x];
    }

    // ---- time loop: both batches per iteration, ONE shared barrier ----
    int cur = 0;
    for (int t = 1; t <= tmaxM; ++t) {
        const int nxt = cur ^ 1;
        const _Float16* HcA = &HA[cur][n * KH];
        const _Float16* HcB = &HB[cur][n * KH];

        // next step's input rows (independent of this step's compute)
        if (t < tmaxM) {
            if (tid < 32) {
                *reinterpret_cast<half2v*>(&HA[nxt][tid * KH + 64]) = HinA[tid][t + 1];
            } else if (tid < 64) {
                int m = tid - 32;
                *reinterpret_cast<half2v*>(&HB[nxt][m * KH + 64]) = HinB[m][t + 1];
            }
        }

        __builtin_amdgcn_s_setprio(1);
        f32x16 dA0, dA1, dB0, dB1;
        #pragma unroll
        for (int j = 0; j < 16; ++j) { dA0[j] = 0.f; dA1[j] = 0.f; dB0[j] = 0.f; dB1[j] = 0.f; }
        #pragma unroll
        for (int kt = 0; kt < 5; ++kt) {
            const int kb = 16 * kt + 8 * hi;
            f16x8 bfA = *reinterpret_cast<const f16x8*>(&HcA[kb]);
            f16x8 bfB = *reinterpret_cast<const f16x8*>(&HcB[kb]);
            dA0 = __builtin_amdgcn_mfma_f32_32x32x16_f16(a[0][kt], bfA, dA0, 0, 0, 0);
            dA1 = __builtin_amdgcn_mfma_f32_32x32x16_f16(a[1][kt], bfA, dA1, 0, 0, 0);
            dB0 = __builtin_amdgcn_mfma_f32_32x32x16_f16(a[0][kt], bfB, dB0, 0, 0, 0);
            dB1 = __builtin_amdgcn_mfma_f32_32x32x16_f16(a[1][kt], bfB, dB1, 0, 0, 0);
        }
        __builtin_amdgcn_s_setprio(0);

        // activations, batch A
        const bool updA = (t <= tmaxnA);
        #pragma unroll
        for (int ti = 0; ti < 2; ++ti) {
            #pragma unroll
            for (int x = 0; x < 4; ++x) {
                const f32x16& d = ti ? dA1 : dA0;
                float ei = EXP2(-d[x]);
                float ef = EXP2(-d[4 + x]);
                float eg = EXP2(-d[8 + x]);
                float eo = EXP2(-d[12 + x]);
                float sf  = RCP(1.f + ef);
                float itg = (1.f - eg) * RCP((1.f + ei) * (1.f + eg));
                float cn  = fmaf(sf, crA[ti][x], itg);
                float ec  = EXP2(-2.f * LOG2E * cn);
                float hn  = (1.f - ec) * RCP((1.f + eo) * (1.f + ec));
                if (updA) { crA[ti][x] = cn; hrA[ti][x] = hn; }
            }
        }
        // activations, batch B
        const bool updB = (t <= tmaxnB);
        #pragma unroll
        for (int ti = 0; ti < 2; ++ti) {
            #pragma unroll
            for (int x = 0; x < 4; ++x) {
                const f32x16& d = ti ? dB1 : dB0;
                float ei = EXP2(-d[x]);
                float ef = EXP2(-d[4 + x]);
                float eg = EXP2(-d[8 + x]);
                float eo = EXP2(-d[12 + x]);
                float sf  = RCP(1.f + ef);
                float itg = (1.f - eg) * RCP((1.f + ei) * (1.f + eg));
                float cn  = fmaf(sf, crB[ti][x], itg);
                float ec  = EXP2(-2.f * LOG2E * cn);
                float hn  = (1.f - ec) * RCP((1.f + eo) * (1.f + ec));
                if (updB) { crB[ti][x] = cn; hrB[ti][x] = hn; }
            }
        }
        if (updA) {
            f16x4 hv0, hv1;
            #pragma unroll
            for (int x = 0; x < 4; ++x) { hv0[x] = (_Float16)hrA[0][x]; hv1[x] = (_Float16)hrA[1][x]; }
            *reinterpret_cast<f16x4*>(&HA[nxt][n * KH + ub0]) = hv0;
            *reinterpret_cast<f16x4*>(&HA[nxt][n * KH + ub1]) = hv1;
        }
        if (updB) {
            f16x4 hv0, hv1;
            #pragma unroll
            for (int x = 0; x < 4; ++x) { hv0[x] = (_Float16)hrB[0][x]; hv1[x] = (_Float16)hrB[1][x]; }
            *reinterpret_cast<f16x4*>(&HB[nxt][n * KH + ub0]) = hv0;
            *reinterpret_cast<f16x4*>(&HB[nxt][n * KH + ub1]) = hv1;
        }
        __syncthreads();               // one barrier covers both batches
        cur = nxt;
    }

    // ---- write final hidden (f32), both batches ----
    {
        float4 vA0 = make_float4(hrA[0][0], hrA[0][1], hrA[0][2], hrA[0][3]);
        float4 vA1 = make_float4(hrA[1][0], hrA[1][1], hrA[1][2], hrA[1][3]);
        *reinterpret_cast<float4*>(&g_je[sidnA * E + ub0]) = vA0;
        *reinterpret_cast<float4*>(&g_je[sidnA * E + ub1]) = vA1;
        float4 vB0 = make_float4(hrB[0][0], hrB[0][1], hrB[0][2], hrB[0][3]);
        float4 vB1 = make_float4(hrB[1][0], hrB[1][1], hrB[1][2], hrB[1][3]);
        *reinterpret_cast<float4*>(&g_je[sidnB * E + ub0]) = vB0;
        *reinterpret_cast<float4*>(&g_je[sidnB * E + ub1]) = vB1;
    }
}

// ---------------------------------------------------------------------------
// Kernel C: dynamic features + attention + output assembly. One block per
// batch element. je-dot 4-way over d; je-mix 4-way over j; twm 2-level
// deterministic reduction.
// ---------------------------------------------------------------------------
__global__ __launch_bounds__(256) void finalize_kernel(
    const float* __restrict__ job_times, const int* __restrict__ precedence,
    const int* __restrict__ job_state,   const float* __restrict__ jest,
    const float* __restrict__ macut,     const float* __restrict__ mksp,
    const float* __restrict__ Wdyn,      const float* __restrict__ bdyn,
    float* __restrict__ out)
{
    const int b   = blockIdx.x;
    const int tid = threadIdx.x;

    __shared__ float rows[J][MM + 2];  // ordered work per (job, machine)
    __shared__ float twmp[MM + 1][5];
    __shared__ float twm[MM + 1];
    __shared__ float feats[J][8];
    __shared__ float aw[J];
    __shared__ float paw[J][4];
    __shared__ float pmix[4][64];
    __shared__ float fbar[8];

    for (int i = tid; i < J * (MM + 2); i += 256)
        reinterpret_cast<float*>(rows)[i] = 0.f;
    __syncthreads();

    // scatter (per j, precedence is a permutation -> distinct cols, no races)
    for (int i = tid; i < J * O; i += 256) {
        const int j = i / O, o = i % O;
        rows[j][precedence[(b * J + j) * MM + o]] = job_times[(b * J + j) * O + o];
    }
    // je-dot partials: thread (j,q) covers d4 in [4q, 4q+4)
    if (tid < 4 * J) {
        const int j = tid >> 2, q = tid & 3;
        const float4* je4 = reinterpret_cast<const float4*>(&g_je[(b * J + j) * E]);
        const float4* hc4 = reinterpret_cast<const float4*>(g_hc);
        float s = 0.f;
        #pragma unroll
        for (int d4 = 4 * q; d4 < 4 * q + 4; ++d4) {
            float4 jv = je4[d4], hv = hc4[d4];
            s = fmaf(jv.x, hv.x, s); s = fmaf(jv.y, hv.y, s);
            s = fmaf(jv.z, hv.z, s); s = fmaf(jv.w, hv.w, s);
        }
        paw[j][q] = s;
    }
    __syncthreads();

    // twm[p] = sum_j rows[j][p], 2-level: (p, chunk-of-10) then 5-way sum
    if (tid < 5 * (MM + 1)) {
        const int p = tid / 5, q = tid % 5;
        float s = 0.f;
        #pragma unroll
        for (int j = 10 * q; j < 10 * q + 10; ++j) s += rows[j][p];
        twmp[p][q] = s;
    }
    __syncthreads();
    if (tid <= MM) {
        twm[tid] = twmp[tid][0] + twmp[tid][1] + twmp[tid][2]
                 + twmp[tid][3] + twmp[tid][4];
    }
    __syncthreads();

    if (tid < J) {
        const int j  = tid;
        const int js = job_state[b * J + j];
        const float* jt = &job_times[(b * J + j) * O];
        float jpt = (js < O) ? jt[js] : 0.f;
        float jst = jest[b * J + j];
        float twr = 0.f;
        for (int o = js; o < O; ++o) twr += jt[o];
        int   mac = (js < O) ? precedence[(b * J + j) * MM + js] : MM;
        float mu  = (mac < MM) ? macut[b * MM + mac] : 0.f;
        float trm = twm[mac] - mu;
        float cm  = mksp[b];
        float f0 = jpt, f1 = jst, f2 = jst + jpt, f3 = twr, f4 = mu, f5 = trm, f6 = cm;
        feats[j][0] = f0; feats[j][1] = f1; feats[j][2] = f2; feats[j][3] = f3;
        feats[j][4] = f4; feats[j][5] = f5; feats[j][6] = f6; feats[j][7] = 0.f;

        float e = g_cproj;
        e = fmaf(f0, g_wproj[0], e); e = fmaf(f1, g_wproj[1], e);
        e = fmaf(f2, g_wproj[2], e); e = fmaf(f3, g_wproj[3], e);
        e = fmaf(f4, g_wproj[4], e); e = fmaf(f5, g_wproj[5], e);
        e = fmaf(f6, g_wproj[6], e);
        aw[j] = e + paw[j][0] + paw[j][1] + paw[j][2] + paw[j][3];
    }
    __syncthreads();

    // wave-parallel softmax over j (first wave only)
    if (tid < 64) {
        float v = (tid < J) ? aw[tid] : -1e30f;
        float mx = v;
        #pragma unroll
        for (int off = 32; off >= 1; off >>= 1) mx = fmaxf(mx, __shfl_xor(mx, off));
        float ex = (tid < J) ? __expf(v - mx) : 0.f;
        float sm = ex;
        #pragma unroll
        for (int off = 32; off >= 1; off >>= 1) sm += __shfl_xor(sm, off);
        if (tid < J) aw[tid] = ex * RCP(sm);
    }
    __syncthreads();

    float* ob = out + b * (2 * DD);  // 384 per batch

    // je-mix partials: thread (q,d) covers j-chunk q
    {
        const int q = tid >> 6, d = tid & 63;
        const int j0 = (q * J) / 4, j1 = ((q + 1) * J) / 4;
        float s = 0.f;
        for (int j = j0; j < j1; ++j)
            s = fmaf(aw[j], g_je[(b * J + j) * E + d], s);
        pmix[q][d] = s;
    }
    if (tid < 8) {
        float s = 0.f;
        for (int j = 0; j < J; ++j) s = fmaf(aw[j], feats[j][tid], s);
        fbar[tid] = s;
    }
    if (tid < DD) ob[tid] = g_hc[tid];
    __syncthreads();
    if (tid < 64) {
        ob[DD + tid] = pmix[0][tid] + pmix[1][tid] + pmix[2][tid] + pmix[3][tid];
    }
    if (tid >= 64 && tid < 192) {
        const int g = tid - 64;     // 0..127
        float s = bdyn[g];
        const float* wd = &Wdyn[g * 7];
        #pragma unroll
        for (int f = 0; f < 7; ++f) s = fmaf(fbar[f], wd[f], s);
        ob[DD + E + g] = s;
    }
}

// ---------------------------------------------------------------------------
extern "C" void kernel_launch(void* const* d_in, const int* in_sizes, int n_in,
                              void* d_out, int out_size, void* d_ws, size_t ws_size,
                              hipStream_t stream)
{
    const float* job_times  = (const float*)d_in[0];
    const int*   precedence = (const int*)  d_in[1];
    const int*   job_state  = (const int*)  d_in[2];
    const float* jest       = (const float*)d_in[3];
    const float* macut      = (const float*)d_in[4];
    const float* mksp       = (const float*)d_in[5];
    const float* Wmac       = (const float*)d_in[6];
    const float* bmac       = (const float*)d_in[7];
    const float* Wjt        = (const float*)d_in[8];
    const float* bjt        = (const float*)d_in[9];
    const float* Wih        = (const float*)d_in[10];
    const float* Whh        = (const float*)d_in[11];
    const float* bih        = (const float*)d_in[12];
    const float* bhh        = (const float*)d_in[13];
    const float* Wdyn       = (const float*)d_in[14];
    const float* bdyn       = (const float*)d_in[15];
    // d_in[16] Wih2, d_in[17] Whh2 are mathematically unused (q_star = h = 0)
    const float* bih2       = (const float*)d_in[18];
    const float* bhh2       = (const float*)d_in[19];

    precompute_kernel<<<1, 1024, 0, stream>>>(Wmac, bmac, Wjt, bjt, Wih, bih, bhh,
                                              Wdyn, bdyn, bih2, bhh2, job_state);
    lstm_kernel<<<NPAIR, 256, 0, stream>>>(job_times, precedence, job_state, Whh);
    finalize_kernel<<<BS, 256, 0, stream>>>(job_times, precedence, job_state, jest,
                                            macut, mksp, Wdyn, bdyn, (float*)d_out);
}

// Round 15
// 101.129 us; speedup vs baseline: 1.1506x; 1.1506x over previous
//
#include <hip/hip_runtime.h>
#include <hip/hip_bf16.h>
#include <math.h>

#define BS 256
#define J  50
#define O  50
#define MM 50
#define E  64
#define NSEQ (BS*J)     // 12800
#define G4 (4*E)        // 256
#define DD 192          // 3*E
#define NBATCH (NSEQ/32) // 400 batches of 32 sequences
#define KH 88            // padded K row stride (176B) — r7/r10-validated layout
#define LOG2E 1.442695041f

typedef _Float16 f16x8 __attribute__((ext_vector_type(8)));
typedef _Float16 f16x4 __attribute__((ext_vector_type(4)));
typedef _Float16 half2v __attribute__((ext_vector_type(2)));
typedef float f32x16 __attribute__((ext_vector_type(16)));

// persistent device scratch (fully rewritten every call)
__device__ float g_u[G4], g_v[G4], g_w[G4];
__device__ float g_h0[E], g_c0[E];
__device__ __align__(16) float g_hc[DD];
__device__ float g_wproj[8];
__device__ float g_cproj;
__device__ float g_je[NSEQ * E];
__device__ int   g_idx[NSEQ];

__device__ __forceinline__ float RCP(float x) {
#if __has_builtin(__builtin_amdgcn_rcpf)
    return __builtin_amdgcn_rcpf(x);
#else
    return __fdividef(1.f, x);
#endif
}
__device__ __forceinline__ float EXP2(float x) {
#if __has_builtin(__builtin_amdgcn_exp2f)
    return __builtin_amdgcn_exp2f(x);
#else
    return exp2f(x);
#endif
}
__device__ __forceinline__ float sigm(float x) {
    return RCP(1.f + __expf(-x));
}
__device__ __forceinline__ float ftanh(float x) {
    float e = __expf(-2.f * x);
    return fmaf(2.f, RCP(1.f + e), -1.f);
}

__device__ __forceinline__ half2v PK(float a, float b) {
#if __has_builtin(__builtin_amdgcn_cvt_pkrtz)
    auto t = __builtin_amdgcn_cvt_pkrtz(a, b);   // __fp16 ext_vector_type(2)
    return __builtin_bit_cast(half2v, t);
#else
    half2v r; r[0] = (_Float16)a; r[1] = (_Float16)b; return r;
#endif
}

// ---------------------------------------------------------------------------
// Placement-aware batch permutation. Blocks b and b+256 co-locate on a CU
// (round-robin dispatch over 256 CUs). Map so equal-length sorted batches
// share a CU and overlap fully (r12/r13 data: lone-WG step chain ~3000cy,
// two co-resident WGs ~1500cy each):
//   block b in [0,144)   -> batch 2b          (even of pair)
//   block b in [256,400) -> batch 2(b-256)+1  (odd twin, same length)
//   block b in [144,256) -> batch 288 + (b-144)  (112 shortest, lone CUs)
// Any permutation is correctness-neutral (each GEMM column depends only on
// its own sequence); a different CU mapping only costs speed.
// ---------------------------------------------------------------------------
__device__ __forceinline__ int batch_of_block(int b) {
    if (b < 144)  return 2 * b;
    if (b >= 256) return 2 * (b - 256) + 1;
    return 288 + (b - 144);
}

// ---------------------------------------------------------------------------
// Kernel A: collapsed input projection (u,v,w), shared first LSTM step
// (h0,c0), Set2Set constant hidden, attention-logit projection, in-block
// LDS-atomic counting sort (1024 threads: 13 passes instead of 50).
// ---------------------------------------------------------------------------
__global__ __launch_bounds__(1024) void precompute_kernel(
    const float* __restrict__ Wmac, const float* __restrict__ bmac,
    const float* __restrict__ Wjt,  const float* __restrict__ bjt,
    const float* __restrict__ Wih,  const float* __restrict__ bih,
    const float* __restrict__ bhh,
    const float* __restrict__ Wdyn, const float* __restrict__ bdyn,
    const float* __restrict__ bih2, const float* __restrict__ bhh2,
    const int*   __restrict__ job_state)
{
    __shared__ float s_hc[DD];
    __shared__ int cnt51[51], cur51[51];
    const int g = threadIdx.x;  // 0..1023

    if (g < 51) cnt51[g] = 0;

    if (g < G4) {
        const float* row = &Wih[g * (2 * E)];
        float u = 0.f, v = 0.f, w = 0.f;
        #pragma unroll 8
        for (int e = 0; e < E; ++e) {
            float w0 = row[e], w1 = row[E + e];
            u = fmaf(w0, Wmac[e], u);
            v = fmaf(w1, Wjt[e], v);
            w = fmaf(w0, bmac[e], fmaf(w1, bjt[e], w));
        }
        g_u[g] = u;
        g_v[g] = v;
        g_w[g] = w + bih[g] + bhh[g];
    }

    // Set2Set with q_star=h=c=0: gates = bih2+bhh2 (constant)
    if (g < DD) {
        float gi = bih2[g]          + bhh2[g];
        float gg = bih2[2 * DD + g] + bhh2[2 * DD + g];
        float go = bih2[3 * DD + g] + bhh2[3 * DD + g];
        float c  = sigm(gi) * ftanh(gg);
        float h  = sigm(go) * ftanh(c);
        s_hc[g] = h;
        g_hc[g] = h;
    }
    __syncthreads();

    // shared t=0 LSTM step: inputs are constants (pv = M, jv = 0), h=c=0
    if (g < E) {
        float ai = fmaf((float)MM, g_u[g],         g_w[g]);
        float ag = fmaf((float)MM, g_u[2 * E + g], g_w[2 * E + g]);
        float ao = fmaf((float)MM, g_u[3 * E + g], g_w[3 * E + g]);
        float c0 = sigm(ai) * ftanh(ag);
        float h0 = sigm(ao) * ftanh(c0);
        g_h0[g] = h0;
        g_c0[g] = c0;
    }

    if (g < 8) {
        float s = 0.f;
        if (g < 7) {
            for (int d = 0; d < 2 * E; ++d) s = fmaf(s_hc[E + d], Wdyn[d * 7 + g], s);
        }
        g_wproj[g] = s;
    }
    if (g == 8) {
        float s = 0.f;
        for (int d = 0; d < 2 * E; ++d) s = fmaf(s_hc[E + d], bdyn[d], s);
        g_cproj = s;
    }

    // ---- counting sort by job_state (ascending js = descending length) ----
    for (int s = g; s < NSEQ; s += 1024)
        atomicAdd(&cnt51[job_state[s]], 1);
    __syncthreads();
    if (g == 0) {
        int run = 0;
        for (int b2 = 0; b2 < 51; ++b2) { cur51[b2] = run; run += cnt51[b2]; }
    }
    __syncthreads();
    for (int s = g; s < NSEQ; s += 1024) {
        int pos = atomicAdd(&cur51[job_state[s]], 1);
        g_idx[pos] = s;
    }
}

// ---------------------------------------------------------------------------
// Kernel B: MFMA-batched LSTM — EXACT r12 structure (best measured: 57us),
// only the blockIdx->batch mapping changed (placement-aware pairing above).
// 4-wave blocks, 32 seqs/WG, double-buffered H, ONE barrier per step, plain
// KH=88 layout, exp2-domain gates (A pre-scaled by log2e, 2*log2e g-rows),
// shared-denominator activations (8 trans/unit), setprio around MFMA.
// ---------------------------------------------------------------------------
__global__ __launch_bounds__(256, 4) void lstm_kernel(
    const float* __restrict__ job_times,   // [BS*J, O]
    const int*   __restrict__ precedence,  // [BS*J, M]
    const int*   __restrict__ job_state,   // [BS*J]
    const float* __restrict__ Whh)         // [256, 64]
{
    __shared__ alignas(16) _Float16 H[2][32 * KH];
    __shared__ half2v Hin[32][O + 1];      // (pv,jv) per (seq col, step t)
    __shared__ int sid_s[32];
    __shared__ int tmx_s[32];
    __shared__ int tmax_sh;

    const int tid  = threadIdx.x;
    const int lane = tid & 63;
    const int wid  = tid >> 6;          // 0..3
    const int n    = lane & 31;         // sequence column (D/B col = lane&31)
    const int hi   = lane >> 5;

    // ---- loop-invariant A fragments (row-permuted G_ext, f16), 2 tiles ----
    const int rl = lane & 31;
    const float sc = ((rl >> 3) == 2) ? (2.f * LOG2E) : LOG2E;  // g-gate rows 2x
    f16x8 a[2][5];
    #pragma unroll
    for (int ti = 0; ti < 2; ++ti) {
        const int tile = wid + 4 * ti;                       // 0..7
        const int grow = (rl >> 3) * 64 + 8 * tile + (rl & 7);
        const float* wr = Whh + grow * 64 + hi * 8;
        #pragma unroll
        for (int kt = 0; kt < 4; ++kt) {
            f16x8 t;
            #pragma unroll
            for (int j = 0; j < 8; ++j) t[j] = (_Float16)(sc * wr[kt * 16 + j]);
            a[ti][kt] = t;
        }
        f16x8 t;
        #pragma unroll
        for (int j = 0; j < 8; ++j) t[j] = (_Float16)0.f;
        if (hi == 0) {              // k=64,65,66 -> u,v,w columns (scaled)
            t[0] = (_Float16)(sc * g_u[grow]);
            t[1] = (_Float16)(sc * g_v[grow]);
            t[2] = (_Float16)(sc * g_w[grow]);
        }
        a[ti][4] = t;
    }

    // this lane's units: tile0 -> ub0..ub0+3, tile1 -> ub1..ub1+3
    const int ub0 = 8 * wid + 4 * hi;
    const int ub1 = ub0 + 32;
    float h0r[2][4], c0r[2][4];
    #pragma unroll
    for (int x = 0; x < 4; ++x) {
        c0r[0][x] = g_c0[ub0 + x]; h0r[0][x] = g_h0[ub0 + x];
        c0r[1][x] = g_c0[ub1 + x]; h0r[1][x] = g_h0[ub1 + x];
    }

    const int b = batch_of_block(blockIdx.x);   // placement-aware pairing

    // ---- batch init ----
    if (tid < 32) {
        int s = g_idx[b * 32 + tid];
        sid_s[tid] = s;
        tmx_s[tid] = O - job_state[s];
    }
    {   // zero both H buffers (covers pad rows 67..87)
        int* Hi = (int*)H;
        for (int i = tid; i < 2 * 32 * KH / 2; i += 256) Hi[i] = 0;
    }
    __syncthreads();
    if (tid == 0) {
        int m = 0;
        for (int i = 0; i < 32; ++i) m = max(m, tmx_s[i]);
        tmax_sh = m;
    }
    // stage all per-step inputs into LDS: Hin[n][t] = (pv, jv) at o = O - t
    for (int i = tid; i < 32 * O; i += 256) {
        const int n2 = i / O;
        const int t2 = i % O + 1;      // 1..50
        const int sid2 = sid_s[n2];
        const int o = O - t2;
        half2v pk = PK((float)precedence[sid2 * MM + o],
                       job_times[sid2 * O + o]);
        Hin[n2][t2] = pk;
        if (t2 == 1) *reinterpret_cast<half2v*>(&H[0][n2 * KH + 64]) = pk;
    }
    {   // write h0 into H[0]
        f16x4 hv0, hv1;
        #pragma unroll
        for (int x = 0; x < 4; ++x) { hv0[x] = (_Float16)h0r[0][x]; hv1[x] = (_Float16)h0r[1][x]; }
        *reinterpret_cast<f16x4*>(&H[0][n * KH + ub0]) = hv0;
        *reinterpret_cast<f16x4*>(&H[0][n * KH + ub1]) = hv1;
    }
    if (tid < 32) {
        H[0][tid * KH + 66] = (_Float16)1.f;   // bias row, both buffers
        H[1][tid * KH + 66] = (_Float16)1.f;
    }
    __syncthreads();

    const int tmaxM = tmax_sh;
    const int tmaxn = tmx_s[n];
    const int sidn  = sid_s[n];

    float cr[2][4], hr[2][4];
    #pragma unroll
    for (int x = 0; x < 4; ++x) {
        cr[0][x] = c0r[0][x]; hr[0][x] = h0r[0][x];
        cr[1][x] = c0r[1][x]; hr[1][x] = h0r[1][x];
    }

    // ---- time loop (lockstep; per-lane masked by tmaxn; 1 barrier/step) ----
    int cur = 0;
    for (int t = 1; t <= tmaxM; ++t) {
        const int nxt = cur ^ 1;
        const _Float16* Hc = &H[cur][n * KH];

        // next step's input row (independent of this step's compute)
        if (tid < 32 && t < tmaxM) {
            *reinterpret_cast<half2v*>(&H[nxt][tid * KH + 64]) = Hin[tid][t + 1];
        }

        __builtin_amdgcn_s_setprio(1);
        f32x16 d0, d1;
        #pragma unroll
        for (int j = 0; j < 16; ++j) { d0[j] = 0.f; d1[j] = 0.f; }
        #pragma unroll
        for (int kt = 0; kt < 5; ++kt) {
            const int kb = 16 * kt + 8 * hi;
            f16x8 bf = *reinterpret_cast<const f16x8*>(&Hc[kb]);
            d0 = __builtin_amdgcn_mfma_f32_32x32x16_f16(a[0][kt], bf, d0, 0, 0, 0);
            d1 = __builtin_amdgcn_mfma_f32_32x32x16_f16(a[1][kt], bf, d1, 0, 0, 0);
        }
        __builtin_amdgcn_s_setprio(0);

        // activations (exp2 domain, shared denominators): 8 trans/unit
        const bool upd = (t <= tmaxn);
        #pragma unroll
        for (int ti = 0; ti < 2; ++ti) {
            #pragma unroll
            for (int x = 0; x < 4; ++x) {
                const f32x16& d = ti ? d1 : d0;
                float ei = EXP2(-d[x]);
                float ef = EXP2(-d[4 + x]);
                float eg = EXP2(-d[8 + x]);
                float eo = EXP2(-d[12 + x]);
                float sf  = RCP(1.f + ef);
                float itg = (1.f - eg) * RCP((1.f + ei) * (1.f + eg));
                float cn  = fmaf(sf, cr[ti][x], itg);
                float ec  = EXP2(-2.f * LOG2E * cn);
                float hn  = (1.f - ec) * RCP((1.f + eo) * (1.f + ec));
                if (upd) { cr[ti][x] = cn; hr[ti][x] = hn; }
            }
        }
        if (upd) {
            f16x4 hv0, hv1;
            #pragma unroll
            for (int x = 0; x < 4; ++x) { hv0[x] = (_Float16)hr[0][x]; hv1[x] = (_Float16)hr[1][x]; }
            *reinterpret_cast<f16x4*>(&H[nxt][n * KH + ub0]) = hv0;
            *reinterpret_cast<f16x4*>(&H[nxt][n * KH + ub1]) = hv1;
        }
        __syncthreads();               // writes to nxt visible; reads of cur done
        cur = nxt;
    }

    // ---- write final hidden (f32) ----
    {
        float4 v0 = make_float4(hr[0][0], hr[0][1], hr[0][2], hr[0][3]);
        float4 v1 = make_float4(hr[1][0], hr[1][1], hr[1][2], hr[1][3]);
        *reinterpret_cast<float4*>(&g_je[sidn * E + ub0]) = v0;
        *reinterpret_cast<float4*>(&g_je[sidn * E + ub1]) = v1;
    }
}

// ---------------------------------------------------------------------------
// Kernel C: dynamic features + attention + output assembly. One block per
// batch element. je-dot 4-way over d; je-mix 4-way over j; twm 2-level
// deterministic reduction.
// ---------------------------------------------------------------------------
__global__ __launch_bounds__(256) void finalize_kernel(
    const float* __restrict__ job_times, const int* __restrict__ precedence,
    const int* __restrict__ job_state,   const float* __restrict__ jest,
    const float* __restrict__ macut,     const float* __restrict__ mksp,
    const float* __restrict__ Wdyn,      const float* __restrict__ bdyn,
    float* __restrict__ out)
{
    const int b   = blockIdx.x;
    const int tid = threadIdx.x;

    __shared__ float rows[J][MM + 2];  // ordered work per (job, machine)
    __shared__ float twmp[MM + 1][5];
    __shared__ float twm[MM + 1];
    __shared__ float feats[J][8];
    __shared__ float aw[J];
    __shared__ float paw[J][4];
    __shared__ float pmix[4][64];
    __shared__ float fbar[8];

    for (int i = tid; i < J * (MM + 2); i += 256)
        reinterpret_cast<float*>(rows)[i] = 0.f;
    __syncthreads();

    // scatter (per j, precedence is a permutation -> distinct cols, no races)
    for (int i = tid; i < J * O; i += 256) {
        const int j = i / O, o = i % O;
        rows[j][precedence[(b * J + j) * MM + o]] = job_times[(b * J + j) * O + o];
    }
    // je-dot partials: thread (j,q) covers d4 in [4q, 4q+4)
    if (tid < 4 * J) {
        const int j = tid >> 2, q = tid & 3;
        const float4* je4 = reinterpret_cast<const float4*>(&g_je[(b * J + j) * E]);
        const float4* hc4 = reinterpret_cast<const float4*>(g_hc);
        float s = 0.f;
        #pragma unroll
        for (int d4 = 4 * q; d4 < 4 * q + 4; ++d4) {
            float4 jv = je4[d4], hv = hc4[d4];
            s = fmaf(jv.x, hv.x, s); s = fmaf(jv.y, hv.y, s);
            s = fmaf(jv.z, hv.z, s); s = fmaf(jv.w, hv.w, s);
        }
        paw[j][q] = s;
    }
    __syncthreads();

    // twm[p] = sum_j rows[j][p], 2-level: (p, chunk-of-10) then 5-way sum
    if (tid < 5 * (MM + 1)) {
        const int p = tid / 5, q = tid % 5;
        float s = 0.f;
        #pragma unroll
        for (int j = 10 * q; j < 10 * q + 10; ++j) s += rows[j][p];
        twmp[p][q] = s;
    }
    __syncthreads();
    if (tid <= MM) {
        twm[tid] = twmp[tid][0] + twmp[tid][1] + twmp[tid][2]
                 + twmp[tid][3] + twmp[tid][4];
    }
    __syncthreads();

    if (tid < J) {
        const int j  = tid;
        const int js = job_state[b * J + j];
        const float* jt = &job_times[(b * J + j) * O];
        float jpt = (js < O) ? jt[js] : 0.f;
        float jst = jest[b * J + j];
        float twr = 0.f;
        for (int o = js; o < O; ++o) twr += jt[o];
        int   mac = (js < O) ? precedence[(b * J + j) * MM + js] : MM;
        float mu  = (mac < MM) ? macut[b * MM + mac] : 0.f;
        float trm = twm[mac] - mu;
        float cm  = mksp[b];
        float f0 = jpt, f1 = jst, f2 = jst + jpt, f3 = twr, f4 = mu, f5 = trm, f6 = cm;
        feats[j][0] = f0; feats[j][1] = f1; feats[j][2] = f2; feats[j][3] = f3;
        feats[j][4] = f4; feats[j][5] = f5; feats[j][6] = f6; feats[j][7] = 0.f;

        float e = g_cproj;
        e = fmaf(f0, g_wproj[0], e); e = fmaf(f1, g_wproj[1], e);
        e = fmaf(f2, g_wproj[2], e); e = fmaf(f3, g_wproj[3], e);
        e = fmaf(f4, g_wproj[4], e); e = fmaf(f5, g_wproj[5], e);
        e = fmaf(f6, g_wproj[6], e);
        aw[j] = e + paw[j][0] + paw[j][1] + paw[j][2] + paw[j][3];
    }
    __syncthreads();

    // wave-parallel softmax over j (first wave only)
    if (tid < 64) {
        float v = (tid < J) ? aw[tid] : -1e30f;
        float mx = v;
        #pragma unroll
        for (int off = 32; off >= 1; off >>= 1) mx = fmaxf(mx, __shfl_xor(mx, off));
        float ex = (tid < J) ? __expf(v - mx) : 0.f;
        float sm = ex;
        #pragma unroll
        for (int off = 32; off >= 1; off >>= 1) sm += __shfl_xor(sm, off);
        if (tid < J) aw[tid] = ex * RCP(sm);
    }
    __syncthreads();

    float* ob = out + b * (2 * DD);  // 384 per batch

    // je-mix partials: thread (q,d) covers j-chunk q
    {
        const int q = tid >> 6, d = tid & 63;
        const int j0 = (q * J) / 4, j1 = ((q + 1) * J) / 4;
        float s = 0.f;
        for (int j = j0; j < j1; ++j)
            s = fmaf(aw[j], g_je[(b * J + j) * E + d], s);
        pmix[q][d] = s;
    }
    if (tid < 8) {
        float s = 0.f;
        for (int j = 0; j < J; ++j) s = fmaf(aw[j], feats[j][tid], s);
        fbar[tid] = s;
    }
    if (tid < DD) ob[tid] = g_hc[tid];
    __syncthreads();
    if (tid < 64) {
        ob[DD + tid] = pmix[0][tid] + pmix[1][tid] + pmix[2][tid] + pmix[3][tid];
    }
    if (tid >= 64 && tid < 192) {
        const int g = tid - 64;     // 0..127
        float s = bdyn[g];
        const float* wd = &Wdyn[g * 7];
        #pragma unroll
        for (int f = 0; f < 7; ++f) s = fmaf(fbar[f], wd[f], s);
        ob[DD + E + g] = s;
    }
}

// ---------------------------------------------------------------------------
extern "C" void kernel_launch(void* const* d_in, const int* in_sizes, int n_in,
                              void* d_out, int out_size, void* d_ws, size_t ws_size,
                              hipStream_t stream)
{
    const float* job_times  = (const float*)d_in[0];
    const int*   precedence = (const int*)  d_in[1];
    const int*   job_state  = (const int*)  d_in[2];
    const float* jest       = (const float*)d_in[3];
    const float* macut      = (const float*)d_in[4];
    const float* mksp       = (const float*)d_in[5];
    const float* Wmac       = (const float*)d_in[6];
    const float* bmac       = (const float*)d_in[7];
    const float* Wjt        = (const float*)d_in[8];
    const float* bjt        = (const float*)d_in[9];
    const float* Wih        = (const float*)d_in[10];
    const float* Whh        = (const float*)d_in[11];
    const float* bih        = (const float*)d_in[12];
    const float* bhh        = (const float*)d_in[13];
    const float* Wdyn       = (const float*)d_in[14];
    const float* bdyn       = (const float*)d_in[15];
    // d_in[16] Wih2, d_in[17] Whh2 are mathematically unused (q_star = h = 0)
    const float* bih2       = (const float*)d_in[18];
    const float* bhh2       = (const float*)d_in[19];

    precompute_kernel<<<1, 1024, 0, stream>>>(Wmac, bmac, Wjt, bjt, Wih, bih, bhh,
                                              Wdyn, bdyn, bih2, bhh2, job_state);
    lstm_kernel<<<NBATCH, 256, 0, stream>>>(job_times, precedence, job_state, Whh);
    finalize_kernel<<<BS, 256, 0, stream>>>(job_times, precedence, job_state, jest,
                                            macut, mksp, Wdyn, bdyn, (float*)d_out);
}

// Round 16
// 81.095 us; speedup vs baseline: 1.4348x; 1.2470x over previous
//
#include <hip/hip_runtime.h>
#include <hip/hip_bf16.h>
#include <math.h>

#define BS 256
#define J  50
#define O  50
#define MM 50
#define E  64
#define NSEQ (BS*J)     // 12800
#define G4 (4*E)        // 256
#define DD 192          // 3*E
#define NBATCH (NSEQ/32) // 400 batches of 32 sequences
#define KH 88            // padded K row stride (176B) — r7/r10-validated layout
#define LOG2E 1.442695041f

typedef _Float16 f16x8 __attribute__((ext_vector_type(8)));
typedef _Float16 f16x4 __attribute__((ext_vector_type(4)));
typedef _Float16 half2v __attribute__((ext_vector_type(2)));
typedef float f32x16 __attribute__((ext_vector_type(16)));

// persistent device scratch (fully rewritten every call)
__device__ float g_u[G4], g_v[G4], g_w[G4];
__device__ float g_h0[E], g_c0[E];
__device__ __align__(16) float g_hc[DD];
__device__ float g_wproj[8];
__device__ float g_cproj;
__device__ float g_je[NSEQ * E];
__device__ int   g_idx[NSEQ];

__device__ __forceinline__ float RCP(float x) {
#if __has_builtin(__builtin_amdgcn_rcpf)
    return __builtin_amdgcn_rcpf(x);
#else
    return __fdividef(1.f, x);
#endif
}
__device__ __forceinline__ float EXP2(float x) {
#if __has_builtin(__builtin_amdgcn_exp2f)
    return __builtin_amdgcn_exp2f(x);
#else
    return exp2f(x);
#endif
}
__device__ __forceinline__ float sigm(float x) {
    return RCP(1.f + __expf(-x));
}
__device__ __forceinline__ float ftanh(float x) {
    float e = __expf(-2.f * x);
    return fmaf(2.f, RCP(1.f + e), -1.f);
}

__device__ __forceinline__ half2v PK(float a, float b) {
#if __has_builtin(__builtin_amdgcn_cvt_pkrtz)
    auto t = __builtin_amdgcn_cvt_pkrtz(a, b);   // __fp16 ext_vector_type(2)
    return __builtin_bit_cast(half2v, t);
#else
    half2v r; r[0] = (_Float16)a; r[1] = (_Float16)b; return r;
#endif
}

// ---------------------------------------------------------------------------
// Kernel A: collapsed input projection (u,v,w), shared first LSTM step
// (h0,c0), Set2Set constant hidden, attention-logit projection, in-block
// LDS-atomic counting sort (1024 threads: 13 passes instead of 50; measured
// worth ~9us vs the 256-thread version).
// ---------------------------------------------------------------------------
__global__ __launch_bounds__(1024) void precompute_kernel(
    const float* __restrict__ Wmac, const float* __restrict__ bmac,
    const float* __restrict__ Wjt,  const float* __restrict__ bjt,
    const float* __restrict__ Wih,  const float* __restrict__ bih,
    const float* __restrict__ bhh,
    const float* __restrict__ Wdyn, const float* __restrict__ bdyn,
    const float* __restrict__ bih2, const float* __restrict__ bhh2,
    const int*   __restrict__ job_state)
{
    __shared__ float s_hc[DD];
    __shared__ int cnt51[51], cur51[51];
    const int g = threadIdx.x;  // 0..1023

    if (g < 51) cnt51[g] = 0;

    if (g < G4) {
        const float* row = &Wih[g * (2 * E)];
        float u = 0.f, v = 0.f, w = 0.f;
        #pragma unroll 8
        for (int e = 0; e < E; ++e) {
            float w0 = row[e], w1 = row[E + e];
            u = fmaf(w0, Wmac[e], u);
            v = fmaf(w1, Wjt[e], v);
            w = fmaf(w0, bmac[e], fmaf(w1, bjt[e], w));
        }
        g_u[g] = u;
        g_v[g] = v;
        g_w[g] = w + bih[g] + bhh[g];
    }

    // Set2Set with q_star=h=c=0: gates = bih2+bhh2 (constant)
    if (g < DD) {
        float gi = bih2[g]          + bhh2[g];
        float gg = bih2[2 * DD + g] + bhh2[2 * DD + g];
        float go = bih2[3 * DD + g] + bhh2[3 * DD + g];
        float c  = sigm(gi) * ftanh(gg);
        float h  = sigm(go) * ftanh(c);
        s_hc[g] = h;
        g_hc[g] = h;
    }
    __syncthreads();

    // shared t=0 LSTM step: inputs are constants (pv = M, jv = 0), h=c=0
    if (g < E) {
        float ai = fmaf((float)MM, g_u[g],         g_w[g]);
        float ag = fmaf((float)MM, g_u[2 * E + g], g_w[2 * E + g]);
        float ao = fmaf((float)MM, g_u[3 * E + g], g_w[3 * E + g]);
        float c0 = sigm(ai) * ftanh(ag);
        float h0 = sigm(ao) * ftanh(c0);
        g_h0[g] = h0;
        g_c0[g] = c0;
    }

    if (g < 8) {
        float s = 0.f;
        if (g < 7) {
            for (int d = 0; d < 2 * E; ++d) s = fmaf(s_hc[E + d], Wdyn[d * 7 + g], s);
        }
        g_wproj[g] = s;
    }
    if (g == 8) {
        float s = 0.f;
        for (int d = 0; d < 2 * E; ++d) s = fmaf(s_hc[E + d], bdyn[d], s);
        g_cproj = s;
    }

    // ---- counting sort by job_state (ascending js = descending length) ----
    for (int s = g; s < NSEQ; s += 1024)
        atomicAdd(&cnt51[job_state[s]], 1);
    __syncthreads();
    if (g == 0) {
        int run = 0;
        for (int b2 = 0; b2 < 51; ++b2) { cur51[b2] = run; run += cnt51[b2]; }
    }
    __syncthreads();
    for (int s = g; s < NSEQ; s += 1024) {
        int pos = atomicAdd(&cur51[job_state[s]], 1);
        g_idx[pos] = s;
    }
}

// ---------------------------------------------------------------------------
// Kernel B: MFMA-batched LSTM — EXACT r12 structure and mapping (batch =
// blockIdx.x), the best measured config (57us). Three scheduling variants
// (work-queue r13, in-WG pairing r14, equal-length permutation r15) all
// measured WORSE; the natural dispatch's long+short CU mix wins.
// 4-wave blocks, 32 seqs/WG, double-buffered H, ONE barrier per step, plain
// KH=88 layout, exp2-domain gates (A pre-scaled by log2e, 2*log2e g-rows),
// shared-denominator activations (8 trans/unit), setprio around MFMA.
// ---------------------------------------------------------------------------
__global__ __launch_bounds__(256, 4) void lstm_kernel(
    const float* __restrict__ job_times,   // [BS*J, O]
    const int*   __restrict__ precedence,  // [BS*J, M]
    const int*   __restrict__ job_state,   // [BS*J]
    const float* __restrict__ Whh)         // [256, 64]
{
    __shared__ alignas(16) _Float16 H[2][32 * KH];
    __shared__ half2v Hin[32][O + 1];      // (pv,jv) per (seq col, step t)
    __shared__ int sid_s[32];
    __shared__ int tmx_s[32];
    __shared__ int tmax_sh;

    const int tid  = threadIdx.x;
    const int lane = tid & 63;
    const int wid  = tid >> 6;          // 0..3
    const int n    = lane & 31;         // sequence column (D/B col = lane&31)
    const int hi   = lane >> 5;

    // ---- loop-invariant A fragments (row-permuted G_ext, f16), 2 tiles ----
    const int rl = lane & 31;
    const float sc = ((rl >> 3) == 2) ? (2.f * LOG2E) : LOG2E;  // g-gate rows 2x
    f16x8 a[2][5];
    #pragma unroll
    for (int ti = 0; ti < 2; ++ti) {
        const int tile = wid + 4 * ti;                       // 0..7
        const int grow = (rl >> 3) * 64 + 8 * tile + (rl & 7);
        const float* wr = Whh + grow * 64 + hi * 8;
        #pragma unroll
        for (int kt = 0; kt < 4; ++kt) {
            f16x8 t;
            #pragma unroll
            for (int j = 0; j < 8; ++j) t[j] = (_Float16)(sc * wr[kt * 16 + j]);
            a[ti][kt] = t;
        }
        f16x8 t;
        #pragma unroll
        for (int j = 0; j < 8; ++j) t[j] = (_Float16)0.f;
        if (hi == 0) {              // k=64,65,66 -> u,v,w columns (scaled)
            t[0] = (_Float16)(sc * g_u[grow]);
            t[1] = (_Float16)(sc * g_v[grow]);
            t[2] = (_Float16)(sc * g_w[grow]);
        }
        a[ti][4] = t;
    }

    // this lane's units: tile0 -> ub0..ub0+3, tile1 -> ub1..ub1+3
    const int ub0 = 8 * wid + 4 * hi;
    const int ub1 = ub0 + 32;
    float h0r[2][4], c0r[2][4];
    #pragma unroll
    for (int x = 0; x < 4; ++x) {
        c0r[0][x] = g_c0[ub0 + x]; h0r[0][x] = g_h0[ub0 + x];
        c0r[1][x] = g_c0[ub1 + x]; h0r[1][x] = g_h0[ub1 + x];
    }

    const int b = blockIdx.x;           // identity mapping (r12, best measured)

    // ---- batch init ----
    if (tid < 32) {
        int s = g_idx[b * 32 + tid];
        sid_s[tid] = s;
        tmx_s[tid] = O - job_state[s];
    }
    {   // zero both H buffers (covers pad rows 67..87)
        int* Hi = (int*)H;
        for (int i = tid; i < 2 * 32 * KH / 2; i += 256) Hi[i] = 0;
    }
    __syncthreads();
    if (tid == 0) {
        int m = 0;
        for (int i = 0; i < 32; ++i) m = max(m, tmx_s[i]);
        tmax_sh = m;
    }
    // stage all per-step inputs into LDS: Hin[n][t] = (pv, jv) at o = O - t
    for (int i = tid; i < 32 * O; i += 256) {
        const int n2 = i / O;
        const int t2 = i % O + 1;      // 1..50
        const int sid2 = sid_s[n2];
        const int o = O - t2;
        half2v pk = PK((float)precedence[sid2 * MM + o],
                       job_times[sid2 * O + o]);
        Hin[n2][t2] = pk;
        if (t2 == 1) *reinterpret_cast<half2v*>(&H[0][n2 * KH + 64]) = pk;
    }
    {   // write h0 into H[0]
        f16x4 hv0, hv1;
        #pragma unroll
        for (int x = 0; x < 4; ++x) { hv0[x] = (_Float16)h0r[0][x]; hv1[x] = (_Float16)h0r[1][x]; }
        *reinterpret_cast<f16x4*>(&H[0][n * KH + ub0]) = hv0;
        *reinterpret_cast<f16x4*>(&H[0][n * KH + ub1]) = hv1;
    }
    if (tid < 32) {
        H[0][tid * KH + 66] = (_Float16)1.f;   // bias row, both buffers
        H[1][tid * KH + 66] = (_Float16)1.f;
    }
    __syncthreads();

    const int tmaxM = tmax_sh;
    const int tmaxn = tmx_s[n];
    const int sidn  = sid_s[n];

    float cr[2][4], hr[2][4];
    #pragma unroll
    for (int x = 0; x < 4; ++x) {
        cr[0][x] = c0r[0][x]; hr[0][x] = h0r[0][x];
        cr[1][x] = c0r[1][x]; hr[1][x] = h0r[1][x];
    }

    // ---- time loop (lockstep; per-lane masked by tmaxn; 1 barrier/step) ----
    int cur = 0;
    for (int t = 1; t <= tmaxM; ++t) {
        const int nxt = cur ^ 1;
        const _Float16* Hc = &H[cur][n * KH];

        // next step's input row (independent of this step's compute)
        if (tid < 32 && t < tmaxM) {
            *reinterpret_cast<half2v*>(&H[nxt][tid * KH + 64]) = Hin[tid][t + 1];
        }

        __builtin_amdgcn_s_setprio(1);
        f32x16 d0, d1;
        #pragma unroll
        for (int j = 0; j < 16; ++j) { d0[j] = 0.f; d1[j] = 0.f; }
        #pragma unroll
        for (int kt = 0; kt < 5; ++kt) {
            const int kb = 16 * kt + 8 * hi;
            f16x8 bf = *reinterpret_cast<const f16x8*>(&Hc[kb]);
            d0 = __builtin_amdgcn_mfma_f32_32x32x16_f16(a[0][kt], bf, d0, 0, 0, 0);
            d1 = __builtin_amdgcn_mfma_f32_32x32x16_f16(a[1][kt], bf, d1, 0, 0, 0);
        }
        __builtin_amdgcn_s_setprio(0);

        // activations (exp2 domain, shared denominators): 8 trans/unit
        const bool upd = (t <= tmaxn);
        #pragma unroll
        for (int ti = 0; ti < 2; ++ti) {
            #pragma unroll
            for (int x = 0; x < 4; ++x) {
                const f32x16& d = ti ? d1 : d0;
                float ei = EXP2(-d[x]);
                float ef = EXP2(-d[4 + x]);
                float eg = EXP2(-d[8 + x]);
                float eo = EXP2(-d[12 + x]);
                float sf  = RCP(1.f + ef);
                float itg = (1.f - eg) * RCP((1.f + ei) * (1.f + eg));
                float cn  = fmaf(sf, cr[ti][x], itg);
                float ec  = EXP2(-2.f * LOG2E * cn);
                float hn  = (1.f - ec) * RCP((1.f + eo) * (1.f + ec));
                if (upd) { cr[ti][x] = cn; hr[ti][x] = hn; }
            }
        }
        if (upd) {
            f16x4 hv0, hv1;
            #pragma unroll
            for (int x = 0; x < 4; ++x) { hv0[x] = (_Float16)hr[0][x]; hv1[x] = (_Float16)hr[1][x]; }
            *reinterpret_cast<f16x4*>(&H[nxt][n * KH + ub0]) = hv0;
            *reinterpret_cast<f16x4*>(&H[nxt][n * KH + ub1]) = hv1;
        }
        __syncthreads();               // writes to nxt visible; reads of cur done
        cur = nxt;
    }

    // ---- write final hidden (f32) ----
    {
        float4 v0 = make_float4(hr[0][0], hr[0][1], hr[0][2], hr[0][3]);
        float4 v1 = make_float4(hr[1][0], hr[1][1], hr[1][2], hr[1][3]);
        *reinterpret_cast<float4*>(&g_je[sidn * E + ub0]) = v0;
        *reinterpret_cast<float4*>(&g_je[sidn * E + ub1]) = v1;
    }
}

// ---------------------------------------------------------------------------
// Kernel C: dynamic features + attention + output assembly. One block per
// batch element. je-dot 4-way over d; je-mix 4-way over j; twm 2-level
// deterministic reduction.
// ---------------------------------------------------------------------------
__global__ __launch_bounds__(256) void finalize_kernel(
    const float* __restrict__ job_times, const int* __restrict__ precedence,
    const int* __restrict__ job_state,   const float* __restrict__ jest,
    const float* __restrict__ macut,     const float* __restrict__ mksp,
    const float* __restrict__ Wdyn,      const float* __restrict__ bdyn,
    float* __restrict__ out)
{
    const int b   = blockIdx.x;
    const int tid = threadIdx.x;

    __shared__ float rows[J][MM + 2];  // ordered work per (job, machine)
    __shared__ float twmp[MM + 1][5];
    __shared__ float twm[MM + 1];
    __shared__ float feats[J][8];
    __shared__ float aw[J];
    __shared__ float paw[J][4];
    __shared__ float pmix[4][64];
    __shared__ float fbar[8];

    for (int i = tid; i < J * (MM + 2); i += 256)
        reinterpret_cast<float*>(rows)[i] = 0.f;
    __syncthreads();

    // scatter (per j, precedence is a permutation -> distinct cols, no races)
    for (int i = tid; i < J * O; i += 256) {
        const int j = i / O, o = i % O;
        rows[j][precedence[(b * J + j) * MM + o]] = job_times[(b * J + j) * O + o];
    }
    // je-dot partials: thread (j,q) covers d4 in [4q, 4q+4)
    if (tid < 4 * J) {
        const int j = tid >> 2, q = tid & 3;
        const float4* je4 = reinterpret_cast<const float4*>(&g_je[(b * J + j) * E]);
        const float4* hc4 = reinterpret_cast<const float4*>(g_hc);
        float s = 0.f;
        #pragma unroll
        for (int d4 = 4 * q; d4 < 4 * q + 4; ++d4) {
            float4 jv = je4[d4], hv = hc4[d4];
            s = fmaf(jv.x, hv.x, s); s = fmaf(jv.y, hv.y, s);
            s = fmaf(jv.z, hv.z, s); s = fmaf(jv.w, hv.w, s);
        }
        paw[j][q] = s;
    }
    __syncthreads();

    // twm[p] = sum_j rows[j][p], 2-level: (p, chunk-of-10) then 5-way sum
    if (tid < 5 * (MM + 1)) {
        const int p = tid / 5, q = tid % 5;
        float s = 0.f;
        #pragma unroll
        for (int j = 10 * q; j < 10 * q + 10; ++j) s += rows[j][p];
        twmp[p][q] = s;
    }
    __syncthreads();
    if (tid <= MM) {
        twm[tid] = twmp[tid][0] + twmp[tid][1] + twmp[tid][2]
                 + twmp[tid][3] + twmp[tid][4];
    }
    __syncthreads();

    if (tid < J) {
        const int j  = tid;
        const int js = job_state[b * J + j];
        const float* jt = &job_times[(b * J + j) * O];
        float jpt = (js < O) ? jt[js] : 0.f;
        float jst = jest[b * J + j];
        float twr = 0.f;
        for (int o = js; o < O; ++o) twr += jt[o];
        int   mac = (js < O) ? precedence[(b * J + j) * MM + js] : MM;
        float mu  = (mac < MM) ? macut[b * MM + mac] : 0.f;
        float trm = twm[mac] - mu;
        float cm  = mksp[b];
        float f0 = jpt, f1 = jst, f2 = jst + jpt, f3 = twr, f4 = mu, f5 = trm, f6 = cm;
        feats[j][0] = f0; feats[j][1] = f1; feats[j][2] = f2; feats[j][3] = f3;
        feats[j][4] = f4; feats[j][5] = f5; feats[j][6] = f6; feats[j][7] = 0.f;

        float e = g_cproj;
        e = fmaf(f0, g_wproj[0], e); e = fmaf(f1, g_wproj[1], e);
        e = fmaf(f2, g_wproj[2], e); e = fmaf(f3, g_wproj[3], e);
        e = fmaf(f4, g_wproj[4], e); e = fmaf(f5, g_wproj[5], e);
        e = fmaf(f6, g_wproj[6], e);
        aw[j] = e + paw[j][0] + paw[j][1] + paw[j][2] + paw[j][3];
    }
    __syncthreads();

    // wave-parallel softmax over j (first wave only)
    if (tid < 64) {
        float v = (tid < J) ? aw[tid] : -1e30f;
        float mx = v;
        #pragma unroll
        for (int off = 32; off >= 1; off >>= 1) mx = fmaxf(mx, __shfl_xor(mx, off));
        float ex = (tid < J) ? __expf(v - mx) : 0.f;
        float sm = ex;
        #pragma unroll
        for (int off = 32; off >= 1; off >>= 1) sm += __shfl_xor(sm, off);
        if (tid < J) aw[tid] = ex * RCP(sm);
    }
    __syncthreads();

    float* ob = out + b * (2 * DD);  // 384 per batch

    // je-mix partials: thread (q,d) covers j-chunk q
    {
        const int q = tid >> 6, d = tid & 63;
        const int j0 = (q * J) / 4, j1 = ((q + 1) * J) / 4;
        float s = 0.f;
        for (int j = j0; j < j1; ++j)
            s = fmaf(aw[j], g_je[(b * J + j) * E + d], s);
        pmix[q][d] = s;
    }
    if (tid < 8) {
        float s = 0.f;
        for (int j = 0; j < J; ++j) s = fmaf(aw[j], feats[j][tid], s);
        fbar[tid] = s;
    }
    if (tid < DD) ob[tid] = g_hc[tid];
    __syncthreads();
    if (tid < 64) {
        ob[DD + tid] = pmix[0][tid] + pmix[1][tid] + pmix[2][tid] + pmix[3][tid];
    }
    if (tid >= 64 && tid < 192) {
        const int g = tid - 64;     // 0..127
        float s = bdyn[g];
        const float* wd = &Wdyn[g * 7];
        #pragma unroll
        for (int f = 0; f < 7; ++f) s = fmaf(fbar[f], wd[f], s);
        ob[DD + E + g] = s;
    }
}

// ---------------------------------------------------------------------------
extern "C" void kernel_launch(void* const* d_in, const int* in_sizes, int n_in,
                              void* d_out, int out_size, void* d_ws, size_t ws_size,
                              hipStream_t stream)
{
    const float* job_times  = (const float*)d_in[0];
    const int*   precedence = (const int*)  d_in[1];
    const int*   job_state  = (const int*)  d_in[2];
    const float* jest       = (const float*)d_in[3];
    const float* macut      = (const float*)d_in[4];
    const float* mksp       = (const float*)d_in[5];
    const float* Wmac       = (const float*)d_in[6];
    const float* bmac       = (const float*)d_in[7];
    const float* Wjt        = (const float*)d_in[8];
    const float* bjt        = (const float*)d_in[9];
    const float* Wih        = (const float*)d_in[10];
    const float* Whh        = (const float*)d_in[11];
    const float* bih        = (const float*)d_in[12];
    const float* bhh        = (const float*)d_in[13];
    const float* Wdyn       = (const float*)d_in[14];
    const float* bdyn       = (const float*)d_in[15];
    // d_in[16] Wih2, d_in[17] Whh2 are mathematically unused (q_star = h = 0)
    const float* bih2       = (const float*)d_in[18];
    const float* bhh2       = (const float*)d_in[19];

    precompute_kernel<<<1, 1024, 0, stream>>>(Wmac, bmac, Wjt, bjt, Wih, bih, bhh,
                                              Wdyn, bdyn, bih2, bhh2, job_state);
    lstm_kernel<<<NBATCH, 256, 0, stream>>>(job_times, precedence, job_state, Whh);
    finalize_kernel<<<BS, 256, 0, stream>>>(job_times, precedence, job_state, jest,
                                            macut, mksp, Wdyn, bdyn, (float*)d_out);
}